// Round 1
// baseline (1216.061 us; speedup 1.0000x reference)
//
#include <hip/hip_runtime.h>
#include <hip/hip_bf16.h>

#define NTOK 4096   // B*S
#define HD   1024   // hidden
#define DD   2048   // expert hidden
#define NE   8      // experts
// top-k = 2

typedef unsigned short u16;
typedef unsigned int   u32;

__device__ __forceinline__ float bf2f(u16 u) {
    u32 v = ((u32)u) << 16;
    return __uint_as_float(v);
}
__device__ __forceinline__ u16 f2bf(float f) {
    __hip_bfloat16 h = __float2bfloat16(f);   // RTN
    return *reinterpret_cast<u16*>(&h);
}

// ---------------- router: 1 wave per token ----------------
__global__ __launch_bounds__(256) void router_k(
        const float* __restrict__ x, const float* __restrict__ gw,
        int* __restrict__ counts, float* __restrict__ sum_probs,
        int* __restrict__ tk_idx, float* __restrict__ tk_w) {
    __shared__ int   bcnt[NE];
    __shared__ float bprob[NE];
    int tid = threadIdx.x;
    if (tid < NE) { bcnt[tid] = 0; bprob[tid] = 0.f; }
    __syncthreads();

    int gtid = blockIdx.x * 256 + tid;
    int t    = gtid >> 6;
    int lane = gtid & 63;

    float acc[NE] = {0.f,0.f,0.f,0.f,0.f,0.f,0.f,0.f};
    const float* xr = x + (size_t)t * HD;
#pragma unroll
    for (int i = 0; i < HD / 64; ++i) {
        int h = lane + i * 64;
        float xv = xr[h];
        const float4* g = reinterpret_cast<const float4*>(gw + (size_t)h * NE);
        float4 g0 = g[0], g1 = g[1];
        acc[0] = fmaf(xv, g0.x, acc[0]); acc[1] = fmaf(xv, g0.y, acc[1]);
        acc[2] = fmaf(xv, g0.z, acc[2]); acc[3] = fmaf(xv, g0.w, acc[3]);
        acc[4] = fmaf(xv, g1.x, acc[4]); acc[5] = fmaf(xv, g1.y, acc[5]);
        acc[6] = fmaf(xv, g1.z, acc[6]); acc[7] = fmaf(xv, g1.w, acc[7]);
    }
#pragma unroll
    for (int off = 32; off >= 1; off >>= 1) {
#pragma unroll
        for (int e = 0; e < NE; ++e) acc[e] += __shfl_xor(acc[e], off);
    }
    // all lanes now hold the 8 logits
    float m = acc[0];
#pragma unroll
    for (int e = 1; e < NE; ++e) m = fmaxf(m, acc[e]);
    float p[NE]; float s = 0.f;
#pragma unroll
    for (int e = 0; e < NE; ++e) { p[e] = expf(acc[e] - m); s += p[e]; }
    float inv = 1.f / s;

    // top-2 (first-occurrence tie-break, matching lax.top_k)
    int i1 = 0; float v1 = p[0];
#pragma unroll
    for (int e = 1; e < NE; ++e) if (p[e] > v1) { v1 = p[e]; i1 = e; }
    int i2 = -1; float v2 = -1.f;
#pragma unroll
    for (int e = 0; e < NE; ++e) if (e != i1 && p[e] > v2) { v2 = p[e]; i2 = e; }
    float wsum = v1 + v2;

    if (lane < NE) atomicAdd(&bprob[lane], p[lane] * inv);
    if (lane == 0) {
        atomicAdd(&bcnt[i1], 1);
        atomicAdd(&bcnt[i2], 1);
        tk_idx[2 * t]     = i1;  tk_idx[2 * t + 1] = i2;
        tk_w[2 * t]       = v1 / wsum;
        tk_w[2 * t + 1]   = v2 / wsum;
    }
    __syncthreads();
    if (tid < NE) {
        if (bcnt[tid]) atomicAdd(&counts[tid], bcnt[tid]);
        atomicAdd(&sum_probs[tid], bprob[tid]);
    }
}

// ---------------- exclusive scan over 8 experts ----------------
__global__ void scan_k(const int* __restrict__ counts, int* __restrict__ offsets) {
    if (threadIdx.x == 0) {
        int o = 0;
        for (int e = 0; e < NE; ++e) { offsets[e] = o; o += counts[e]; }
    }
}

// ---------------- scatter tokens into expert-grouped slots ----------------
__global__ __launch_bounds__(256) void scatter_k(
        const int* __restrict__ tk_idx, const int* __restrict__ offsets,
        int* __restrict__ cursor, int* __restrict__ slot_tok,
        int* __restrict__ inv_slot) {
    int t = blockIdx.x * 256 + threadIdx.x;
    if (t >= NTOK) return;
#pragma unroll
    for (int k = 0; k < 2; ++k) {
        int e = tk_idx[2 * t + k];
        int pos = atomicAdd(&cursor[e], 1);
        int s = offsets[e] + pos;
        slot_tok[s] = t;
        inv_slot[2 * t + k] = s;
    }
}

// ---------------- grouped GEMM1: h = gelu(x_gathered @ W1[e] + b1[e]) -> bf16
// tiles: BM=128, BN=128, BK=16; 256 threads, 8x8 register blocking
__global__ __launch_bounds__(256) void gemm1_k(
        const float* __restrict__ x, const float* __restrict__ W1,
        const float* __restrict__ b1, const int* __restrict__ counts,
        const int* __restrict__ offsets, const int* __restrict__ slot_tok,
        u16* __restrict__ hbuf) {
    int e = blockIdx.z;
    int cnt = counts[e];
    int m0 = blockIdx.y * 128;
    if (m0 >= cnt) return;
    int n0 = blockIdx.x * 128;
    int base = offsets[e];

    __shared__ float xs[16][132];
    __shared__ float ws[16][132];
    __shared__ int ids[128];

    int tid = threadIdx.x;
    if (tid < 128) ids[tid] = (m0 + tid < cnt) ? slot_tok[base + m0 + tid] : -1;
    __syncthreads();

    const float* W1e = W1 + (size_t)e * HD * DD;
    int ty = tid >> 4, tx = tid & 15;
    float acc[8][8] = {};

    for (int k0 = 0; k0 < HD; k0 += 16) {
        // stage gathered x (transposed into xs[k][row])
#pragma unroll
        for (int i = 0; i < 2; ++i) {
            int r  = (tid >> 2) + i * 64;
            int c4 = (tid & 3) * 4;
            int tok = ids[r];
            float4 v = make_float4(0.f, 0.f, 0.f, 0.f);
            if (tok >= 0) v = *reinterpret_cast<const float4*>(x + (size_t)tok * HD + k0 + c4);
            xs[c4 + 0][r] = v.x; xs[c4 + 1][r] = v.y;
            xs[c4 + 2][r] = v.z; xs[c4 + 3][r] = v.w;
        }
        // stage W1 tile
#pragma unroll
        for (int i = 0; i < 2; ++i) {
            int kk = (tid >> 5) + i * 8;
            int c  = (tid & 31) * 4;
            *reinterpret_cast<float4*>(&ws[kk][c]) =
                *reinterpret_cast<const float4*>(W1e + (size_t)(k0 + kk) * DD + n0 + c);
        }
        __syncthreads();
#pragma unroll
        for (int kk = 0; kk < 16; ++kk) {
            float4 a0 = *reinterpret_cast<float4*>(&xs[kk][ty * 8]);
            float4 a1 = *reinterpret_cast<float4*>(&xs[kk][ty * 8 + 4]);
            float4 b0 = *reinterpret_cast<float4*>(&ws[kk][tx * 8]);
            float4 b1v = *reinterpret_cast<float4*>(&ws[kk][tx * 8 + 4]);
            float a[8] = {a0.x,a0.y,a0.z,a0.w,a1.x,a1.y,a1.z,a1.w};
            float b[8] = {b0.x,b0.y,b0.z,b0.w,b1v.x,b1v.y,b1v.z,b1v.w};
#pragma unroll
            for (int i = 0; i < 8; ++i)
#pragma unroll
                for (int j = 0; j < 8; ++j)
                    acc[i][j] = fmaf(a[i], b[j], acc[i][j]);
        }
        __syncthreads();
    }
    // epilogue: +b1, exact gelu, -> bf16
#pragma unroll
    for (int i = 0; i < 8; ++i) {
        int r = ty * 8 + i;
        if (m0 + r >= cnt) continue;
        size_t slot = (size_t)(base + m0 + r);
        u16 tmp[8];
#pragma unroll
        for (int j = 0; j < 8; ++j) {
            int col = n0 + tx * 8 + j;
            float v = acc[i][j] + b1[e * DD + col];
            float g = 0.5f * v * (1.f + erff(v * 0.70710678118654752f));
            tmp[j] = f2bf(g);
        }
        *reinterpret_cast<uint4*>(hbuf + slot * DD + n0 + tx * 8) =
            *reinterpret_cast<uint4*>(tmp);
    }
}

// ---------------- grouped GEMM2: y = h @ W2[e] -> bf16 per-slot ----------------
__global__ __launch_bounds__(256) void gemm2_k(
        const u16* __restrict__ hbuf, const float* __restrict__ W2,
        const int* __restrict__ counts, const int* __restrict__ offsets,
        u16* __restrict__ ybuf) {
    int e = blockIdx.z;
    int cnt = counts[e];
    int m0 = blockIdx.y * 128;
    if (m0 >= cnt) return;
    int n0 = blockIdx.x * 128;
    int base = offsets[e];

    __shared__ float xs[16][132];
    __shared__ float ws[16][132];

    const float* W2e = W2 + (size_t)e * DD * HD;
    int tid = threadIdx.x;
    int ty = tid >> 4, tx = tid & 15;
    float acc[8][8] = {};

    for (int k0 = 0; k0 < DD; k0 += 16) {
        // stage h rows (bf16 -> f32, transposed)
        {
            int row  = tid >> 1;
            int half = tid & 1;
            if (m0 + row < cnt) {
                uint4 q = *reinterpret_cast<const uint4*>(
                    hbuf + (size_t)(base + m0 + row) * DD + k0 + half * 8);
                xs[half * 8 + 0][row] = bf2f((u16)(q.x & 0xffff));
                xs[half * 8 + 1][row] = bf2f((u16)(q.x >> 16));
                xs[half * 8 + 2][row] = bf2f((u16)(q.y & 0xffff));
                xs[half * 8 + 3][row] = bf2f((u16)(q.y >> 16));
                xs[half * 8 + 4][row] = bf2f((u16)(q.z & 0xffff));
                xs[half * 8 + 5][row] = bf2f((u16)(q.z >> 16));
                xs[half * 8 + 6][row] = bf2f((u16)(q.w & 0xffff));
                xs[half * 8 + 7][row] = bf2f((u16)(q.w >> 16));
            } else {
#pragma unroll
                for (int j = 0; j < 8; ++j) xs[half * 8 + j][row] = 0.f;
            }
        }
        // stage W2 tile
#pragma unroll
        for (int i = 0; i < 2; ++i) {
            int kk = (tid >> 5) + i * 8;
            int c  = (tid & 31) * 4;
            *reinterpret_cast<float4*>(&ws[kk][c]) =
                *reinterpret_cast<const float4*>(W2e + (size_t)(k0 + kk) * HD + n0 + c);
        }
        __syncthreads();
#pragma unroll
        for (int kk = 0; kk < 16; ++kk) {
            float4 a0 = *reinterpret_cast<float4*>(&xs[kk][ty * 8]);
            float4 a1 = *reinterpret_cast<float4*>(&xs[kk][ty * 8 + 4]);
            float4 b0 = *reinterpret_cast<float4*>(&ws[kk][tx * 8]);
            float4 b1v = *reinterpret_cast<float4*>(&ws[kk][tx * 8 + 4]);
            float a[8] = {a0.x,a0.y,a0.z,a0.w,a1.x,a1.y,a1.z,a1.w};
            float b[8] = {b0.x,b0.y,b0.z,b0.w,b1v.x,b1v.y,b1v.z,b1v.w};
#pragma unroll
            for (int i = 0; i < 8; ++i)
#pragma unroll
                for (int j = 0; j < 8; ++j)
                    acc[i][j] = fmaf(a[i], b[j], acc[i][j]);
        }
        __syncthreads();
    }
#pragma unroll
    for (int i = 0; i < 8; ++i) {
        int r = ty * 8 + i;
        if (m0 + r >= cnt) continue;
        size_t slot = (size_t)(base + m0 + r);
        u16 tmp[8];
#pragma unroll
        for (int j = 0; j < 8; ++j) tmp[j] = f2bf(acc[i][j]);
        *reinterpret_cast<uint4*>(ybuf + slot * HD + n0 + tx * 8) =
            *reinterpret_cast<uint4*>(tmp);
    }
}

// ---------------- combine: out[t] = sum_k w_k * (y[slot_k] + b2[e_k]) ----------------
__global__ __launch_bounds__(256) void combine_k(
        const int* __restrict__ tk_idx, const float* __restrict__ tk_w,
        const int* __restrict__ inv_slot, const u16* __restrict__ ybuf,
        const float* __restrict__ b2, float* __restrict__ out) {
    int gtid = blockIdx.x * 256 + threadIdx.x;
    int t = gtid >> 6;
    int lane = gtid & 63;
    int e0 = tk_idx[2 * t], e1 = tk_idx[2 * t + 1];
    float w0 = tk_w[2 * t], w1 = tk_w[2 * t + 1];
    int s0 = inv_slot[2 * t], s1 = inv_slot[2 * t + 1];

#pragma unroll
    for (int i = 0; i < 2; ++i) {
        int c = lane * 8 + i * 512;
        uint4 q0 = *reinterpret_cast<const uint4*>(ybuf + (size_t)s0 * HD + c);
        uint4 q1 = *reinterpret_cast<const uint4*>(ybuf + (size_t)s1 * HD + c);
        float y0[8] = {bf2f((u16)(q0.x&0xffff)), bf2f((u16)(q0.x>>16)),
                       bf2f((u16)(q0.y&0xffff)), bf2f((u16)(q0.y>>16)),
                       bf2f((u16)(q0.z&0xffff)), bf2f((u16)(q0.z>>16)),
                       bf2f((u16)(q0.w&0xffff)), bf2f((u16)(q0.w>>16))};
        float y1[8] = {bf2f((u16)(q1.x&0xffff)), bf2f((u16)(q1.x>>16)),
                       bf2f((u16)(q1.y&0xffff)), bf2f((u16)(q1.y>>16)),
                       bf2f((u16)(q1.z&0xffff)), bf2f((u16)(q1.z>>16)),
                       bf2f((u16)(q1.w&0xffff)), bf2f((u16)(q1.w>>16))};
        float r[8];
#pragma unroll
        for (int j = 0; j < 8; ++j) {
            float v0 = y0[j] + b2[e0 * HD + c + j];
            float v1 = y1[j] + b2[e1 * HD + c + j];
            r[j] = w0 * v0 + w1 * v1;
        }
        float* op = out + (size_t)t * HD + c;
        *reinterpret_cast<float4*>(op)     = make_float4(r[0], r[1], r[2], r[3]);
        *reinterpret_cast<float4*>(op + 4) = make_float4(r[4], r[5], r[6], r[7]);
    }
}

// ---------------- aux loss finalize ----------------
__global__ void finalize_k(const int* __restrict__ counts,
                           const float* __restrict__ sum_probs,
                           float* __restrict__ out_aux) {
    if (threadIdx.x == 0) {
        double s = 0.0;
        for (int e = 0; e < NE; ++e) s += (double)counts[e] * (double)sum_probs[e];
        // aux = E/(B*NTOK) * sum = sum / 1024
        out_aux[0] = (float)(s * (8.0 / (2.0 * (double)NTOK)));
    }
}

extern "C" void kernel_launch(void* const* d_in, const int* in_sizes, int n_in,
                              void* d_out, int out_size, void* d_ws, size_t ws_size,
                              hipStream_t stream) {
    const float* x   = (const float*)d_in[0];
    const float* gw  = (const float*)d_in[1];
    const float* W1  = (const float*)d_in[2];
    const float* b1  = (const float*)d_in[3];
    const float* W2  = (const float*)d_in[4];
    const float* b2  = (const float*)d_in[5];
    float* out = (float*)d_out;

    char* ws = (char*)d_ws;
    int*   counts    = (int*)(ws + 0);
    int*   cursor    = (int*)(ws + 32);
    int*   offsets   = (int*)(ws + 64);
    float* sum_probs = (float*)(ws + 128);
    int*   tk_idx    = (int*)(ws + 256);                       // 8192 ints
    float* tk_w      = (float*)(ws + 256 + 32768);             // 8192 floats
    int*   slot_tok  = (int*)(ws + 256 + 65536);               // 8192 ints
    int*   inv_slot  = (int*)(ws + 256 + 98304);               // 8192 ints
    u16*   hbuf      = (u16*)(ws + 131328 + 768);              // align 256: 132096
    // hbuf: 8192*2048*2 = 33,554,432 B
    u16*   ybuf      = (u16*)(ws + 132096 + 33554432);         // 8192*1024*2 = 16,777,216 B

    hipMemsetAsync(ws, 0, 512, stream);

    router_k<<<NTOK / 4, 256, 0, stream>>>(x, gw, counts, sum_probs, tk_idx, tk_w);
    scan_k<<<1, 64, 0, stream>>>(counts, offsets);
    scatter_k<<<NTOK / 256, 256, 0, stream>>>(tk_idx, offsets, cursor, slot_tok, inv_slot);
    gemm1_k<<<dim3(DD / 128, NTOK / 128, NE), 256, 0, stream>>>(
        x, W1, b1, counts, offsets, slot_tok, hbuf);
    gemm2_k<<<dim3(HD / 128, NTOK / 128, NE), 256, 0, stream>>>(
        hbuf, W2, counts, offsets, ybuf);
    combine_k<<<NTOK / 4, 256, 0, stream>>>(tk_idx, tk_w, inv_slot, ybuf, b2, out);
    finalize_k<<<1, 64, 0, stream>>>(counts, sum_probs, out + (size_t)NTOK * HD);
}

// Round 2
// 274.203 us; speedup vs baseline: 4.4349x; 4.4349x over previous
//
#include <hip/hip_runtime.h>
#include <hip/hip_bf16.h>

#define NTOK 4096   // B*S
#define HD   1024   // hidden
#define DD   2048   // expert hidden
#define NE   8      // experts
#define SLOTS (2*NTOK)
#define SLOTS_PAD (SLOTS + 128)

typedef unsigned short u16;
typedef unsigned int   u32;
typedef __attribute__((ext_vector_type(8))) __bf16 bf16x8;
typedef __attribute__((ext_vector_type(4))) float  f32x4;

__device__ __forceinline__ float bf2f(u16 u) {
    u32 v = ((u32)u) << 16;
    return __uint_as_float(v);
}
__device__ __forceinline__ u16 f2bf(float f) {
    __hip_bfloat16 h = __float2bfloat16(f);   // RTN
    return *reinterpret_cast<u16*>(&h);
}

__device__ __forceinline__ void gload_lds16(const void* g, void* l) {
    __builtin_amdgcn_global_load_lds(
        (__attribute__((address_space(1))) void*)g,
        (__attribute__((address_space(3))) void*)l,
        16, 0, 0);
}

// ---------------- convert x -> bf16 ----------------
__global__ __launch_bounds__(256) void cvt_x_k(const float* __restrict__ src,
                                               u16* __restrict__ dst) {
    size_t i = ((size_t)blockIdx.x * 256 + threadIdx.x) * 8;
    float4 v0 = *reinterpret_cast<const float4*>(src + i);
    float4 v1 = *reinterpret_cast<const float4*>(src + i + 4);
    u16 tmp[8] = {f2bf(v0.x), f2bf(v0.y), f2bf(v0.z), f2bf(v0.w),
                  f2bf(v1.x), f2bf(v1.y), f2bf(v1.z), f2bf(v1.w)};
    *reinterpret_cast<uint4*>(dst + i) = *reinterpret_cast<uint4*>(tmp);
}

// ---------------- convert + transpose weights: src [e][R][C] f32 -> dst [e][C][R] bf16
template<int R, int C>
__global__ __launch_bounds__(256) void cvtT_k(const float* __restrict__ src,
                                              u16* __restrict__ dst) {
    __shared__ u16 tile[32][33];
    int e  = blockIdx.z;
    int c0 = blockIdx.x * 32, r0 = blockIdx.y * 32;
    int tx = threadIdx.x & 31, ty = threadIdx.x >> 5;   // 32 x 8
    const float* s = src + (size_t)e * R * C;
    u16* d = dst + (size_t)e * C * R;
#pragma unroll
    for (int j = 0; j < 4; ++j) {
        int r = ty + j * 8;
        tile[r][tx] = f2bf(s[(size_t)(r0 + r) * C + c0 + tx]);
    }
    __syncthreads();
#pragma unroll
    for (int j = 0; j < 4; ++j) {
        int cc = ty + j * 8;
        d[(size_t)(c0 + cc) * R + r0 + tx] = tile[tx][cc];
    }
}

// ---------------- router: 1 wave per token ----------------
__global__ __launch_bounds__(256) void router_k(
        const float* __restrict__ x, const float* __restrict__ gw,
        int* __restrict__ counts, float* __restrict__ sum_probs,
        int* __restrict__ tk_idx, float* __restrict__ tk_w) {
    __shared__ int   bcnt[NE];
    __shared__ float bprob[NE];
    int tid = threadIdx.x;
    if (tid < NE) { bcnt[tid] = 0; bprob[tid] = 0.f; }
    __syncthreads();

    int gtid = blockIdx.x * 256 + tid;
    int t    = gtid >> 6;
    int lane = gtid & 63;

    float acc[NE] = {0.f,0.f,0.f,0.f,0.f,0.f,0.f,0.f};
    const float* xr = x + (size_t)t * HD;
#pragma unroll
    for (int i = 0; i < HD / 64; ++i) {
        int h = lane + i * 64;
        float xv = xr[h];
        const float4* g = reinterpret_cast<const float4*>(gw + (size_t)h * NE);
        float4 g0 = g[0], g1 = g[1];
        acc[0] = fmaf(xv, g0.x, acc[0]); acc[1] = fmaf(xv, g0.y, acc[1]);
        acc[2] = fmaf(xv, g0.z, acc[2]); acc[3] = fmaf(xv, g0.w, acc[3]);
        acc[4] = fmaf(xv, g1.x, acc[4]); acc[5] = fmaf(xv, g1.y, acc[5]);
        acc[6] = fmaf(xv, g1.z, acc[6]); acc[7] = fmaf(xv, g1.w, acc[7]);
    }
#pragma unroll
    for (int off = 32; off >= 1; off >>= 1) {
#pragma unroll
        for (int e = 0; e < NE; ++e) acc[e] += __shfl_xor(acc[e], off);
    }
    float m = acc[0];
#pragma unroll
    for (int e = 1; e < NE; ++e) m = fmaxf(m, acc[e]);
    float p[NE]; float s = 0.f;
#pragma unroll
    for (int e = 0; e < NE; ++e) { p[e] = expf(acc[e] - m); s += p[e]; }
    float inv = 1.f / s;

    int i1 = 0; float v1 = p[0];
#pragma unroll
    for (int e = 1; e < NE; ++e) if (p[e] > v1) { v1 = p[e]; i1 = e; }
    int i2 = -1; float v2 = -1.f;
#pragma unroll
    for (int e = 0; e < NE; ++e) if (e != i1 && p[e] > v2) { v2 = p[e]; i2 = e; }
    float wsum = v1 + v2;

    if (lane < NE) atomicAdd(&bprob[lane], p[lane] * inv);
    if (lane == 0) {
        atomicAdd(&bcnt[i1], 1);
        atomicAdd(&bcnt[i2], 1);
        tk_idx[2 * t]     = i1;  tk_idx[2 * t + 1] = i2;
        tk_w[2 * t]       = v1 / wsum;
        tk_w[2 * t + 1]   = v2 / wsum;
    }
    __syncthreads();
    if (tid < NE) {
        if (bcnt[tid]) atomicAdd(&counts[tid], bcnt[tid]);
        atomicAdd(&sum_probs[tid], bprob[tid]);
    }
}

// ---------------- exclusive scan over 8 experts ----------------
__global__ void scan_k(const int* __restrict__ counts, int* __restrict__ offsets) {
    if (threadIdx.x == 0) {
        int o = 0;
        for (int e = 0; e < NE; ++e) { offsets[e] = o; o += counts[e]; }
    }
}

// ---------------- scatter tokens into expert-grouped slots ----------------
__global__ __launch_bounds__(256) void scatter_k(
        const int* __restrict__ tk_idx, const int* __restrict__ offsets,
        int* __restrict__ cursor, int* __restrict__ slot_tok,
        int* __restrict__ inv_slot) {
    int t = blockIdx.x * 256 + threadIdx.x;
    if (t >= NTOK) return;
#pragma unroll
    for (int k = 0; k < 2; ++k) {
        int e = tk_idx[2 * t + k];
        int pos = atomicAdd(&cursor[e], 1);
        int s = offsets[e] + pos;
        slot_tok[s] = t;
        inv_slot[2 * t + k] = s;
    }
}

// ---------------- grouped MFMA GEMM (m97 structure) ----------------
// C[m][n] = sum_k A[m][k] * Bt[n][k]   per expert, 128x128 tile, BK=32
// 4 waves 2x2, each wave 64x64 via 4x4 frags of v_mfma_f32_16x16x32_bf16
template<int KD, int ND, bool GATHER, bool GELU>
__global__ __launch_bounds__(256) void gemm_mfma_k(
        const u16* __restrict__ A,      // GATHER: xb [NTOK][KD]; else hbuf [SLOTS_PAD][KD]
        const u16* __restrict__ Bt,     // [NE][ND][KD]
        const float* __restrict__ bias, // GELU: b1 [NE][ND]
        const int* __restrict__ counts, const int* __restrict__ offsets,
        const int* __restrict__ slot_tok,
        u16* __restrict__ outb) {       // [SLOTS_PAD][ND]
    int e   = blockIdx.z;
    int cnt = counts[e];
    int m0  = blockIdx.y * 128;
    if (m0 >= cnt) return;
    int n0   = blockIdx.x * 128;
    int base = offsets[e];

    __shared__ u16 Asm[128 * 32];
    __shared__ u16 Bsm[128 * 32];
    __shared__ int ids[128];

    int tid  = threadIdx.x;
    int lane = tid & 63;
    int w    = tid >> 6;

    if constexpr (GATHER) {
        if (tid < 128) ids[tid] = (m0 + tid < cnt) ? slot_tok[base + m0 + tid] : 0;
    }
    __syncthreads();

    const u16* Bte = Bt + (size_t)e * ND * KD;
    int srow = w * 16 + (lane >> 2);      // staged row within half-tile
    int skk  = (lane & 3) * 8;            // staged k offset (elems)

    size_t arow0, arow1;
    if constexpr (GATHER) {
        arow0 = (size_t)ids[srow]      * KD;
        arow1 = (size_t)ids[srow + 64] * KD;
    } else {
        arow0 = (size_t)(base + m0 + srow)      * KD;
        arow1 = (size_t)(base + m0 + srow + 64) * KD;
    }
    size_t brow0 = (size_t)(n0 + srow)      * KD;
    size_t brow1 = (size_t)(n0 + srow + 64) * KD;

    int wr = w >> 1, wc = w & 1;
    int lrow = lane & 15, lk8 = (lane >> 4) * 8;

    f32x4 acc[4][4];
#pragma unroll
    for (int m = 0; m < 4; ++m)
#pragma unroll
        for (int n = 0; n < 4; ++n) acc[m][n] = {0.f, 0.f, 0.f, 0.f};

    for (int k0 = 0; k0 < KD; k0 += 32) {
        gload_lds16(A + arow0 + k0 + skk,   (char*)Asm + w * 1024);
        gload_lds16(A + arow1 + k0 + skk,   (char*)Asm + 4096 + w * 1024);
        gload_lds16(Bte + brow0 + k0 + skk, (char*)Bsm + w * 1024);
        gload_lds16(Bte + brow1 + k0 + skk, (char*)Bsm + 4096 + w * 1024);
        __syncthreads();   // drains vmcnt(0) -> LDS tiles ready

        bf16x8 af[4], bf[4];
#pragma unroll
        for (int m = 0; m < 4; ++m)
            af[m] = *reinterpret_cast<const bf16x8*>(&Asm[(wr * 64 + m * 16 + lrow) * 32 + lk8]);
#pragma unroll
        for (int n = 0; n < 4; ++n)
            bf[n] = *reinterpret_cast<const bf16x8*>(&Bsm[(wc * 64 + n * 16 + lrow) * 32 + lk8]);
#pragma unroll
        for (int m = 0; m < 4; ++m)
#pragma unroll
            for (int n = 0; n < 4; ++n)
                acc[m][n] = __builtin_amdgcn_mfma_f32_16x16x32_bf16(
                    af[m], bf[n], acc[m][n], 0, 0, 0);
        __syncthreads();   // LDS reusable next iter
    }

    // epilogue: C/D layout row=(lane>>4)*4+i, col=lane&15 (m89-verified)
    int lhi4 = (lane >> 4) * 4;
#pragma unroll
    for (int n = 0; n < 4; ++n) {
        int col = n0 + wc * 64 + n * 16 + lrow;
        float bv = 0.f;
        if constexpr (GELU) bv = bias[(size_t)e * ND + col];
#pragma unroll
        for (int m = 0; m < 4; ++m) {
            int rbase = wr * 64 + m * 16 + lhi4;
#pragma unroll
            for (int i = 0; i < 4; ++i) {
                int row = rbase + i;
                if (m0 + row < cnt) {
                    float v = acc[m][n][i];
                    if constexpr (GELU) {
                        v += bv;
                        v = 0.5f * v * (1.f + erff(v * 0.70710678118654752f));
                    }
                    outb[(size_t)(base + m0 + row) * ND + col] = f2bf(v);
                }
            }
        }
    }
}

// ---------------- combine: out[t] = sum_k w_k * (y[slot_k] + b2[e_k]) ----------------
__global__ __launch_bounds__(256) void combine_k(
        const int* __restrict__ tk_idx, const float* __restrict__ tk_w,
        const int* __restrict__ inv_slot, const u16* __restrict__ ybuf,
        const float* __restrict__ b2, float* __restrict__ out) {
    int gtid = blockIdx.x * 256 + threadIdx.x;
    int t = gtid >> 6;
    int lane = gtid & 63;
    int e0 = tk_idx[2 * t], e1 = tk_idx[2 * t + 1];
    float w0 = tk_w[2 * t], w1 = tk_w[2 * t + 1];
    int s0 = inv_slot[2 * t], s1 = inv_slot[2 * t + 1];

#pragma unroll
    for (int i = 0; i < 2; ++i) {
        int c = lane * 8 + i * 512;
        uint4 q0 = *reinterpret_cast<const uint4*>(ybuf + (size_t)s0 * HD + c);
        uint4 q1 = *reinterpret_cast<const uint4*>(ybuf + (size_t)s1 * HD + c);
        float y0[8] = {bf2f((u16)(q0.x&0xffff)), bf2f((u16)(q0.x>>16)),
                       bf2f((u16)(q0.y&0xffff)), bf2f((u16)(q0.y>>16)),
                       bf2f((u16)(q0.z&0xffff)), bf2f((u16)(q0.z>>16)),
                       bf2f((u16)(q0.w&0xffff)), bf2f((u16)(q0.w>>16))};
        float y1[8] = {bf2f((u16)(q1.x&0xffff)), bf2f((u16)(q1.x>>16)),
                       bf2f((u16)(q1.y&0xffff)), bf2f((u16)(q1.y>>16)),
                       bf2f((u16)(q1.z&0xffff)), bf2f((u16)(q1.z>>16)),
                       bf2f((u16)(q1.w&0xffff)), bf2f((u16)(q1.w>>16))};
        float r[8];
#pragma unroll
        for (int j = 0; j < 8; ++j) {
            float v0 = y0[j] + b2[e0 * HD + c + j];
            float v1 = y1[j] + b2[e1 * HD + c + j];
            r[j] = w0 * v0 + w1 * v1;
        }
        float* op = out + (size_t)t * HD + c;
        *reinterpret_cast<float4*>(op)     = make_float4(r[0], r[1], r[2], r[3]);
        *reinterpret_cast<float4*>(op + 4) = make_float4(r[4], r[5], r[6], r[7]);
    }
}

// ---------------- aux loss finalize ----------------
__global__ void finalize_k(const int* __restrict__ counts,
                           const float* __restrict__ sum_probs,
                           float* __restrict__ out_aux) {
    if (threadIdx.x == 0) {
        double s = 0.0;
        for (int e = 0; e < NE; ++e) s += (double)counts[e] * (double)sum_probs[e];
        out_aux[0] = (float)(s * (8.0 / (2.0 * (double)NTOK)));
    }
}

extern "C" void kernel_launch(void* const* d_in, const int* in_sizes, int n_in,
                              void* d_out, int out_size, void* d_ws, size_t ws_size,
                              hipStream_t stream) {
    const float* x   = (const float*)d_in[0];
    const float* gw  = (const float*)d_in[1];
    const float* W1  = (const float*)d_in[2];
    const float* b1  = (const float*)d_in[3];
    const float* W2  = (const float*)d_in[4];
    const float* b2  = (const float*)d_in[5];
    float* out = (float*)d_out;

    char* ws = (char*)d_ws;
    // meta block [0,512): counts@0, cursor@32, offsets@64, sum_probs@128
    int*   counts    = (int*)(ws + 0);
    int*   cursor    = (int*)(ws + 32);
    int*   offsets   = (int*)(ws + 64);
    float* sum_probs = (float*)(ws + 128);
    int*   tk_idx    = (int*)(ws + 512);                 // 32768 B
    float* tk_w      = (float*)(ws + 33280);             // 32768 B
    int*   slot_tok  = (int*)(ws + 66048);               // 32768 B
    int*   inv_slot  = (int*)(ws + 98816);               // 32768 B
    u16*   xb        = (u16*)(ws + 131584);              // 8,388,608 B
    u16*   W1t       = (u16*)(ws + 8520192);             // 33,554,432 B [ybuf aliases: 17,039,360 B]
    u16*   W2t       = (u16*)(ws + 42074624);            // 33,554,432 B
    u16*   hbuf      = (u16*)(ws + 75629056);            // 34,078,720 B (padded rows)
    u16*   ybuf      = W1t;                              // W1t dead after gemm1
    // total = 109,707,776 B

    hipMemsetAsync(ws, 0, 512, stream);

    cvt_x_k<<<NTOK * HD / (256 * 8), 256, 0, stream>>>(x, xb);
    cvtT_k<HD, DD><<<dim3(DD / 32, HD / 32, NE), 256, 0, stream>>>(W1, W1t);
    cvtT_k<DD, HD><<<dim3(HD / 32, DD / 32, NE), 256, 0, stream>>>(W2, W2t);
    router_k<<<NTOK / 4, 256, 0, stream>>>(x, gw, counts, sum_probs, tk_idx, tk_w);
    scan_k<<<1, 64, 0, stream>>>(counts, offsets);
    scatter_k<<<NTOK / 256, 256, 0, stream>>>(tk_idx, offsets, cursor, slot_tok, inv_slot);

    gemm_mfma_k<HD, DD, true, true><<<dim3(DD / 128, NTOK / 128, NE), 256, 0, stream>>>(
        xb, W1t, b1, counts, offsets, slot_tok, hbuf);
    gemm_mfma_k<DD, HD, false, false><<<dim3(HD / 128, NTOK / 128, NE), 256, 0, stream>>>(
        hbuf, W2t, nullptr, counts, offsets, slot_tok, ybuf);

    combine_k<<<NTOK / 4, 256, 0, stream>>>(tk_idx, tk_w, inv_slot, ybuf, b2, out);
    finalize_k<<<1, 64, 0, stream>>>(counts, sum_probs, out + (size_t)NTOK * HD);
}